// Round 8
// baseline (97.252 us; speedup 1.0000x reference)
//
#include <hip/hip_runtime.h>

// 8-level sym8 wavelet packet transform, B=128 rows of L0=65536, f32.
// 3 fused kernels: F01 (levels 0-1), F23 (levels 2-3), F47 (levels 4-7).
// Lengths: 65536->32775->16395->8205->4110->2062->1038->526->270.
// POLYPHASE LDS layout: every subband tile stored as split even/odd streams
// (E[i]=s[2i], O[i]=s[2i+1]). The stride-2 16-tap FIR becomes two stride-1
// 8-tap FIRs; NO=4 output groups read 6 ds_read_b128 at dense 16B lane
// stride (aligned) per 128 FMA and write 4 dense b64. Reflect margins stay
// within parity classes; producers mirror-write them via eo_put.

#define BT 512

// Even/odd split of the flipped (cross-correlation) dec filters.
__device__ __constant__ float FLE[8] = {
     0.0018899503327594609f, -0.01495225833704823f,  0.049137179673607506f,
    -0.05194583810770904f,   0.7771857517005235f,   -0.061273359067658524f,
     0.007607487324917605f, -0.0005421323317911481f };
__device__ __constant__ float FLO[8] = {
    -0.0003029205147213668f, 0.003808752013890615f, -0.027219029917056003f,
     0.3644418948353314f,    0.4813596512583722f,   -0.1432942383508097f,
     0.03169508781149298f,  -0.0033824159510061256f };
__device__ __constant__ float FHE[8] = {
     0.0033824159510061256f, -0.03169508781149298f,  0.1432942383508097f,
    -0.4813596512583722f,   -0.3644418948353314f,    0.027219029917056003f,
    -0.003808752013890615f,  0.0003029205147213668f };
__device__ __constant__ float FHO[8] = {
    -0.0005421323317911481f, 0.007607487324917605f, -0.061273359067658524f,
     0.7771857517005235f,   -0.05194583810770904f,   0.049137179673607506f,
    -0.01495225833704823f,   0.0018899503327594609f };

__device__ __forceinline__ int reflect(int q, int L) {
    q = (q < 0) ? -q : q;
    return (q >= L) ? (2 * L - 2 - q) : q;
}

// Margined E/O ext arrays: position q (may be virtual/negative) -> slot.
// Even q -> E[8 + q/2]; odd q -> O[8 + (q-1)/2]. Arithmetic >> gives floor.
__device__ __forceinline__ void eo_put(float* __restrict__ E, float* __restrict__ O,
                                       int q, float v) {
    ((q & 1) ? O : E)[8 + (q >> 1)] = v;
}

__device__ __forceinline__ void read12(const float* __restrict__ b, int w0,
                                       float* __restrict__ r) {
#pragma unroll
    for (int k = 0; k < 3; ++k) {
        const float4 v = *reinterpret_cast<const float4*>(&b[w0 + 4 * k]);
        r[4 * k] = v.x; r[4 * k + 1] = v.y; r[4 * k + 2] = v.z; r[4 * k + 3] = v.w;
    }
}

// 4 consecutive outputs, both filters, from E/O windows. Tap for output d:
// e[OFF+d+s], o[OFF+d+s], s=0..7.
template <int OFF>
__device__ __forceinline__ void conv4(const float e[12], const float o[12],
                                      float lo[4], float hi[4]) {
#pragma unroll
    for (int d = 0; d < 4; ++d) { lo[d] = 0.f; hi[d] = 0.f; }
#pragma unroll
    for (int s = 0; s < 8; ++s) {
        const float fle = FLE[s], flo = FLO[s], fhe = FHE[s], fho = FHO[s];
#pragma unroll
        for (int d = 0; d < 4; ++d) {
            const float ev = e[OFF + d + s], ov = o[OFF + d + s];
            lo[d] = fmaf(ev, fle, lo[d]);
            lo[d] = fmaf(ov, flo, lo[d]);
            hi[d] = fmaf(ev, fhe, hi[d]);
            hi[d] = fmaf(ov, fho, hi[d]);
        }
    }
}

// Scalar polyphase conv at window start s of margin-less E/O arrays.
__device__ __forceinline__ void conv1s(const float* __restrict__ E,
                                       const float* __restrict__ O,
                                       int s, float& lo, float& hi) {
    lo = hi = 0.f;
#pragma unroll
    for (int k = 0; k < 8; ++k) {
        const float ev = E[s + k], ov = O[s + k];
        lo = fmaf(ev, FLE[k], lo);
        lo = fmaf(ov, FLO[k], lo);
        hi = fmaf(ev, FHE[k], hi);
        hi = fmaf(ov, FHO[k], hi);
    }
}

// ---------------- Fused two-level kernel (levels k, k+1) ----------------
// x-tile (E/O, no margins) covers virtual A-tile [a_lo, a_lo+WA);
// A-phase writes E/O A-tile (no margins, virtual coverage); B-phase reads
// dense windows and stores interleaved float4 to global.
template <int LIN, int LA, int LB, int SIN, int SOUT, int MB>
__global__ __launch_bounds__(BT, 8) void dwt_pair_eo(
    const float* __restrict__ x, float* __restrict__ y) {
    constexpr int WA  = 2 * MB + 14;            // virtual A-tile width
    constexpr int WX  = 2 * WA + 14;            // x coverage
    constexpr int EXS = ((WX / 2) + 3) & ~3;    // x-tile E/O stride (+overread)
    constexpr int KA  = WA / 2;                 // A-tile entries per parity
    constexpr int KAp = (KA + 1 + 3) & ~3;      // padded (+overread)
    __shared__ __align__(16) float xt[2 * EXS];
    __shared__ __align__(16) float at[4 * KAp];  // E_lo | O_lo | E_hi | O_hi

    const int seg  = blockIdx.x;
    const int n    = blockIdx.y;
    const int b0   = seg * MB;
    const int a_lo = 2 * b0 - 14;
    const int px0  = 2 * a_lo - 14;             // even
    const float* row = x + (size_t)n * (size_t)SIN;
    float* Ex = xt;
    float* Ox = xt + EXS;

    // ---- x-tile fill (deinterleave; reflect folded in for edge blocks) ----
    if (px0 >= 0 && px0 + WX <= LIN) {
        const float2* rp = reinterpret_cast<const float2*>(row + px0);
        for (int k = threadIdx.x; k < WX / 2; k += BT) {
            const float2 v = rp[k];
            Ex[k] = v.x; Ox[k] = v.y;
        }
    } else {
        for (int k = threadIdx.x; k < WX / 2; k += BT) {
            const int p = px0 + 2 * k;
            Ex[k] = row[reflect(p, LIN)];
            Ox[k] = row[reflect(p + 1, LIN)];
        }
    }
    __syncthreads();

    // ---- A-phase: tile-local positions s0..s0+3 (s = a - a_lo) ----
    const int jbmax = ((b0 + MB < LB) ? (b0 + MB) : LB) - 1;
    const int smax  = 2 * (jbmax - b0) + 15;    // max tile-s read by B
    constexpr int GPSA = (WA + 3) / 4;
    float* EAl = at;
    float* OAl = at + KAp;
    float* EAh = at + 2 * KAp;
    float* OAh = at + 3 * KAp;
    for (int g = threadIdx.x; g < GPSA; g += BT) {
        const int s0 = 4 * g;
        if (s0 > smax) continue;
        const int a0 = a_lo + s0;
        float lo[4], hi[4];
        if (a0 >= 0 && a0 + 3 < LA) {
            float e[12], o[12];
            read12(Ex, s0, e);
            read12(Ox, s0, o);
            conv4<0>(e, o, lo, hi);
        } else {
#pragma unroll
            for (int d = 0; d < 4; ++d) {       // reflect in A-index space
                int s2 = reflect(a0 + d, LA) - a_lo;
                s2 = (s2 < 0) ? 0 : ((s2 > EXS - 9) ? (EXS - 9) : s2);
                conv1s(Ex, Ox, s2, lo[d], hi[d]);
            }
        }
        if (s0 + 3 < WA) {
            *reinterpret_cast<float2*>(&EAl[2 * g]) = make_float2(lo[0], lo[2]);
            *reinterpret_cast<float2*>(&OAl[2 * g]) = make_float2(lo[1], lo[3]);
            *reinterpret_cast<float2*>(&EAh[2 * g]) = make_float2(hi[0], hi[2]);
            *reinterpret_cast<float2*>(&OAh[2 * g]) = make_float2(hi[1], hi[3]);
        } else {
#pragma unroll
            for (int d = 0; d < 4; ++d)
                if (s0 + d < WA) {
                    const int s = s0 + d;
                    ((s & 1) ? OAl : EAl)[s >> 1] = lo[d];
                    ((s & 1) ? OAh : EAh)[s >> 1] = hi[d];
                }
        }
    }
    __syncthreads();

    // ---- B-phase: dense windows from A-tile, interleaved global store ----
    constexpr int GPSB = MB / 4;                // MB % 4 == 0
    for (int g = threadIdx.x; g < 2 * GPSB; g += BT) {
        const int sA  = (g >= GPSB) ? 1 : 0;
        const int v   = g - sA * GPSB;
        const int jb0 = b0 + 4 * v;
        if (jb0 >= LB) continue;
        const float* EA = at + 2 * sA * KAp;
        const float* OA = EA + KAp;
        float e[12], o[12];
        read12(EA, 4 * v, e);
        read12(OA, 4 * v, o);
        float lo[4], hi[4];
        conv4<0>(e, o, lo, hi);
        float* y0 = y + (size_t)(4 * n + 2 * sA) * (size_t)SOUT + (size_t)jb0;
        float* y1 = y0 + SOUT;
        if (jb0 + 3 < LB) {
            *reinterpret_cast<float4*>(y0) = make_float4(lo[0], lo[1], lo[2], lo[3]);
            *reinterpret_cast<float4*>(y1) = make_float4(hi[0], hi[1], hi[2], hi[3]);
        } else {
#pragma unroll
            for (int i = 0; i < 4; ++i)
                if (jb0 + i < LB) { y0[i] = lo[i]; y1[i] = hi[i]; }
        }
    }
}

// ---------------- Fused four-level kernel (levels 4-7) ----------------
// Subband ext layout: [E: 8 margin | H | 12 margin+pad][O: same], SE mult 4.
template <int Ls, int P, int Sin, int Sout, bool LOG>
__device__ __forceinline__ void stage_eo(const float* __restrict__ inb,
                                         float* __restrict__ outb,
                                         float* __restrict__ outg) {
    constexpr int H    = Ls / 2;
    constexpr int LOUT = H + 7;                 // even for all our stages
    constexpr int GPS  = (LOUT + 3) / 4;
    constexpr int SEi  = Sin / 2;
    constexpr int SEo  = Sout / 2;
    for (int g = threadIdx.x; g < P * GPS; g += BT) {
        const int p  = g / GPS;                 // compile-time divisor
        const int u  = g - p * GPS;
        const int j0 = 4 * u;
        const float* Ei = inb + p * Sin;
        const float* Oi = Ei + SEi;
        float e[12], o[12];
        read12(Ei, 4 * u, e);                   // ext words 4u..4u+11 (idx j0-8..j0+3)
        read12(Oi, 4 * u, o);
        float lo[4], hi[4];
        conv4<1>(e, o, lo, hi);
        if (LOG) {
            float r0[4], r1[4];
#pragma unroll
            for (int d = 0; d < 4; ++d) {
                r0[d] = __logf(fmaf(lo[d], lo[d], 1e-12f));
                r1[d] = __logf(fmaf(hi[d], hi[d], 1e-12f));
            }
            float* y0 = outg + (2 * p) * 270 + j0;
            float* y1 = y0 + 270;
            if (j0 + 3 < 270) {
                *reinterpret_cast<float2*>(y0)     = make_float2(r0[0], r0[1]);
                *reinterpret_cast<float2*>(y0 + 2) = make_float2(r0[2], r0[3]);
                *reinterpret_cast<float2*>(y1)     = make_float2(r1[0], r1[1]);
                *reinterpret_cast<float2*>(y1 + 2) = make_float2(r1[2], r1[3]);
            } else {                            // 270 % 4 == 2: exactly 2 valid
                *reinterpret_cast<float2*>(y0) = make_float2(r0[0], r0[1]);
                *reinterpret_cast<float2*>(y1) = make_float2(r1[0], r1[1]);
            }
        } else {
            float* El = outb + (2 * p) * Sout;
            float* Ol = El + SEo;
            float* Eh = outb + (2 * p + 1) * Sout;
            float* Oh = Eh + SEo;
            if (j0 + 3 < LOUT) {                // main: dense b64 writes
                *reinterpret_cast<float2*>(&El[8 + 2 * u]) = make_float2(lo[0], lo[2]);
                *reinterpret_cast<float2*>(&Ol[8 + 2 * u]) = make_float2(lo[1], lo[3]);
                *reinterpret_cast<float2*>(&Eh[8 + 2 * u]) = make_float2(hi[0], hi[2]);
                *reinterpret_cast<float2*>(&Oh[8 + 2 * u]) = make_float2(hi[1], hi[3]);
            } else {                            // last group: guarded scalar
#pragma unroll
                for (int d = 0; d < 4; ++d)
                    if (j0 + d < LOUT) {
                        eo_put(El, Ol, j0 + d, lo[d]);
                        eo_put(Eh, Oh, j0 + d, hi[d]);
                    }
            }
            if (j0 <= 14 || j0 >= LOUT - 18) {  // margin mirror writes
#pragma unroll
                for (int d = 0; d < 4; ++d) {
                    const int j = j0 + d;
                    if (j >= 1 && j <= 14) {
                        eo_put(El, Ol, -j, lo[d]);
                        eo_put(Eh, Oh, -j, hi[d]);
                    }
                    if (j >= LOUT - 15 && j <= LOUT - 2) {
                        eo_put(El, Ol, 2 * LOUT - 2 - j, lo[d]);
                        eo_put(Eh, Oh, 2 * LOUT - 2 - j, hi[d]);
                    }
                }
            }
        }
    }
}

__global__ __launch_bounds__(BT, 8) void dwt_quad_eo(
    const float* __restrict__ x, float* __restrict__ y) {
    // SE strides: L=4110:2076 L=2062:1052 L=1038:540 L=526:284 (all mult 4)
    __shared__ __align__(16) float bufA[4320];  // in 4152 | s2-out 4x1080
    __shared__ __align__(16) float bufB[4544];  // s1-out 2x2104 | s3-out 8x568

    const int m = blockIdx.x;
    const float* row = x + (size_t)m * 4112;
    float* Ex = bufA;
    float* Ox = bufA + 2076;
    for (int i = threadIdx.x; i < 2055; i += BT) {
        const float2 v = reinterpret_cast<const float2*>(row)[i];
        Ex[8 + i] = v.x;
        Ox[8 + i] = v.y;
        if (i >= 1 && i <= 7)       eo_put(Ex, Ox, -2 * i, v.x);          // x[2i] -> -2i
        if (i <= 6)                 eo_put(Ex, Ox, -(2 * i + 1), v.y);    // x[2i+1]
        if (i >= 2048)              eo_put(Ex, Ox, 8218 - 2 * i, v.x);    // 2*4110-2-p
        if (i >= 2047 && i <= 2053) eo_put(Ex, Ox, 8217 - 2 * i, v.y);
    }
    __syncthreads();
    stage_eo<4110, 1, 4152, 2104, false>(bufA, bufB, nullptr);  // -> 2x2062
    __syncthreads();
    stage_eo<2062, 2, 2104, 1080, false>(bufB, bufA, nullptr);  // -> 4x1038
    __syncthreads();
    stage_eo<1038, 4, 1080, 568, false>(bufA, bufB, nullptr);   // -> 8x526
    __syncthreads();
    stage_eo<526, 8, 568, 0, true>(bufB, nullptr, y + (size_t)m * 4320); // 16x270
}

extern "C" void kernel_launch(void* const* d_in, const int* in_sizes, int n_in,
                              void* d_out, int out_size, void* d_ws, size_t ws_size,
                              hipStream_t stream) {
    const float* in = (const float*)d_in[0];
    float* out = (float*)d_out;
    float* wsA = (float*)d_ws;              // lev1: 512 rows, stride 16396
    float* wsB = (float*)d_ws + 8400000;    // lev3: 2048 rows, stride 4112

    // F01: 65536 -> 32775 -> 16395; MB=1024, 17 segs
    { dim3 g(17, 128); dwt_pair_eo<65536, 32775, 16395, 65536, 16396, 1024>
          <<<g, BT, 0, stream>>>(in, wsA); }
    // F23: 16395 -> 8205 -> 4110; MB=1028, 4 segs
    { dim3 g(4, 512);  dwt_pair_eo<16395, 8205, 4110, 16396, 4112, 1028>
          <<<g, BT, 0, stream>>>(wsA, wsB); }
    // F47: 4110 -> 2062 -> 1038 -> 526 -> 270(+log)
    dwt_quad_eo<<<2048, BT, 0, stream>>>(wsB, out);
}